// Round 8
// baseline (101.417 us; speedup 1.0000x reference)
//
#include <hip/hip_runtime.h>
#include <stdint.h>

#define NEGC (-1.0e9f)

typedef __attribute__((ext_vector_type(8))) short bf16x8;
typedef __attribute__((ext_vector_type(4))) float f32x4;

#define VMCNT(n) asm volatile("s_waitcnt vmcnt(" #n ")" ::: "memory")
#define LGKMCNT0 asm volatile("s_waitcnt lgkmcnt(0)" ::: "memory")
#define SBARM asm volatile("s_barrier" ::: "memory")

// precomputed seq2 forms: hi/lo split bf16 [b][m][d], and transposed bf16 [b][d][m]
__device__ __align__(16) unsigned short g_S2H[32u * 512u * 128u];
__device__ __align__(16) unsigned short g_S2L[32u * 512u * 128u];
__device__ __align__(16) unsigned short g_VT[32u * 128u * 512u];

__device__ __forceinline__ unsigned short f2bf(float f) {
    union { float f; unsigned int u; } v; v.f = f;
    unsigned int r = v.u + 0x7fffu + ((v.u >> 16) & 1u);
    return (unsigned short)(r >> 16);
}
__device__ __forceinline__ float bf2f(unsigned short h) {
    union { float f; unsigned int u; } v; v.u = ((unsigned int)h) << 16;
    return v.f;
}

__device__ __forceinline__ void gl_lds16(const void* g, void* l) {
    __builtin_amdgcn_global_load_lds(
        (const __attribute__((address_space(1))) unsigned int*)g,
        (__attribute__((address_space(3))) unsigned int*)l, 16, 0, 0);
}

// ---- prep: seq2 -> bf16 hi/lo split + transposed bf16. 512 blocks (full GPU). ----
__global__ __launch_bounds__(256) void k_prep(const float* __restrict__ seq2) {
    __shared__ unsigned short Lh[32 * 130];
    const int b = blockIdx.x >> 4, c = blockIdx.x & 15, t = threadIdx.x;
    const int m0 = c * 32;

    const float4* src = (const float4*)(seq2 + (size_t)(b * 512 + m0) * 128);
    ushort4* dh = (ushort4*)(g_S2H + (size_t)(b * 512 + m0) * 128);
    ushort4* dl = (ushort4*)(g_S2L + (size_t)(b * 512 + m0) * 128);
#pragma unroll
    for (int p = 0; p < 4; ++p) {
        int idx = p * 256 + t;
        int row = idx >> 5, c4 = idx & 31;
        float4 v = src[idx];
        float vs[4] = {v.x, v.y, v.z, v.w};
        unsigned short hh[4], ll[4];
#pragma unroll
        for (int i = 0; i < 4; ++i) { hh[i] = f2bf(vs[i]); ll[i] = f2bf(vs[i] - bf2f(hh[i])); }
        ushort4 uh{hh[0], hh[1], hh[2], hh[3]};
        ushort4 ul{ll[0], ll[1], ll[2], ll[3]};
        dh[idx] = uh;
        dl[idx] = ul;
#pragma unroll
        for (int i = 0; i < 4; ++i) Lh[row * 130 + c4 * 4 + i] = hh[i];
    }
    __syncthreads();

    const int d = t >> 1, sub = t & 1;
    unsigned short pk[16];
#pragma unroll
    for (int j = 0; j < 16; ++j) pk[j] = Lh[(sub * 16 + j) * 130 + d];
    unsigned short* dst = g_VT + (size_t)(b * 128 + d) * 512 + m0 + sub * 16;
    *(bf16x8*)dst = *(bf16x8*)pk;
    *(bf16x8*)(dst + 8) = *(bf16x8*)(pk + 8);
}

// ---- LDS layout (bytes) ----
// staging region @0 (32K): phase A = K dbuf 2x16K {KH 8K|KL 8K};
//                          phase C = VT dbuf 2x16K [16 d][512 m];
//                          end     = Pex f32[2][16][132] (16.9K)
// M2 u8 @32768 | REDm @33280 | REDs @33536
#define M2OFF 32768
#define REDMOFF 33280
#define REDSOFF 33536
#define LDS_TOTAL 33792

__global__ __launch_bounds__(256, 3) void bidir_main(
    const float* __restrict__ seq1,
    const int* __restrict__ m1, const int* __restrict__ m2,
    float* __restrict__ out0, float* __restrict__ a2out,
    float* __restrict__ a1log)
{
    __shared__ __align__(16) char smem[LDS_TOTAL];

    const int t = threadIdx.x, lane = t & 63, w = t >> 6;
    const int wr = w >> 1, wc = w & 1, q = lane >> 4, fr = lane & 15;
    const int orig = blockIdx.x;
    const int swzb = (orig & 7) * 256 + (orig >> 3);   // XCD-contiguous
    const int b = swzb >> 6, n0 = (swzb & 63) << 5;

    unsigned char* M2u8 = (unsigned char*)(smem + M2OFF);
    float* REDm = (float*)(smem + REDMOFF);
    float* REDs = (float*)(smem + REDSOFF);

    // K-tile stage (IDENTICAL to R7): tile kt = m in [kt*16,+16) u [256+kt*16,+16), hi+lo.
    auto stageK = [&](int buf, int kt) {
        const unsigned short* sb = (w < 2) ? g_S2H : g_S2L;
        const int h = w & 1;
        const char* srcb = (const char*)(sb + (size_t)(b * 512 + h * 256 + kt * 16) * 128);
        char* dstb = smem + buf * 16384 + (w >> 1) * 8192 + h * 4096;
#pragma unroll
        for (int i = 0; i < 4; ++i) {
            int r = i * 4 + q;
            int so = r * 256 + ((fr * 16) ^ ((r & 7) << 4));
            gl_lds16(srcb + so, dstb + i * 1024);
        }
    };
    // VT tile stage: tile dt = V^T rows [dt*16,+16) x all 512 m. Wave w: rows [w*4,+4).
    auto stageT = [&](int buf, int dt) {
        char* dstb = smem + buf * 16384 + w * 4096;
#pragma unroll
        for (int i = 0; i < 4; ++i) {
            int row = w * 4 + i;                          // d-local
            int cb = (lane * 16) ^ ((row & 7) << 4);
            size_t so = ((size_t)(b * 128 + dt * 16 + row)) * 1024 + cb;
            gl_lds16((const char*)g_VT + so, dstb + i * 1024);
        }
    };

    // ---- prologue ----
    stageK(0, 0);

    if (t < 128) {                      // m2 mask as u8
        int4 v = ((const int4*)(m2 + b * 512))[t];
        uchar4 u{(unsigned char)v.x, (unsigned char)v.y, (unsigned char)v.z, (unsigned char)v.w};
        *(uchar4*)(M2u8 + t * 4) = u;
    }

    // Q fragments (B-operand now; same per-lane data/layout as before): rows wr*16+fr.
    bf16x8 qh[4], ql[4];
    {
        const float* qp = seq1 + (size_t)(b * 2048 + n0 + wr * 16 + fr) * 128;
#pragma unroll
        for (int ks = 0; ks < 4; ++ks) {
            float4 v0 = *(const float4*)(qp + ks * 32 + q * 8);
            float4 v1 = *(const float4*)(qp + ks * 32 + q * 8 + 4);
            float vs[8] = {v0.x, v0.y, v0.z, v0.w, v1.x, v1.y, v1.z, v1.w};
            unsigned short hh[8], ll[8];
#pragma unroll
            for (int j = 0; j < 8; ++j) { hh[j] = f2bf(vs[j]); ll[j] = f2bf(vs[j] - bf2f(hh[j])); }
            qh[ks] = *(bf16x8*)hh;
            ql[ks] = *(bf16x8*)ll;
        }
    }

    stageK(1, 1);

    f32x4 acc[8][2];
#pragma unroll
    for (int i = 0; i < 8; ++i) {
        acc[i][0] = (f32x4){0.f, 0.f, 0.f, 0.f};
        acc[i][1] = (f32x4){0.f, 0.f, 0.f, 0.f};
    }

    // ---- phase A: S^T = K . Q^T (split bf16, 3 MFMA, SWAPPED ARGS) ----
    // acc[kt>>1][kt&1] lane (q,fr): S^T[m = wc*256 + kt*16 + q*4+r][n = wr*16 + fr]
#pragma unroll
    for (int kt = 0; kt < 16; ++kt) {
        if (kt == 15) { VMCNT(0); } else { VMCNT(4); }
        SBARM;
        {
            const char* KH = smem + (kt & 1) * 16384;
            const char* KL = KH + 8192;
            const int rrow = wc * 16 + fr;
            const int sw = (fr & 7) << 4;
            f32x4 a = acc[kt >> 1][kt & 1];
#pragma unroll
            for (int ks = 0; ks < 4; ++ks) {
                int off = (rrow * 256 + ks * 64 + q * 16) ^ sw;
                bf16x8 kh = *(const bf16x8*)(KH + off);
                bf16x8 kl = *(const bf16x8*)(KL + off);
                a = __builtin_amdgcn_mfma_f32_16x16x32_bf16(kl, qh[ks], a, 0, 0, 0);
                a = __builtin_amdgcn_mfma_f32_16x16x32_bf16(kh, ql[ks], a, 0, 0, 0);
                a = __builtin_amdgcn_mfma_f32_16x16x32_bf16(kh, qh[ks], a, 0, 0, 0);
            }
            acc[kt >> 1][kt & 1] = a;
        }
        LGKMCNT0;
        SBARM;
        if (kt < 14) stageK(kt & 1, kt + 2);
    }

    // ---- phase B: softmax. lane owns row n = wr*16+fr; m = wc*256+mt*32+s*16+q*4+r ----
#pragma unroll
    for (int mt = 0; mt < 8; ++mt)
#pragma unroll
        for (int s = 0; s < 2; ++s) {
            uchar4 mv = *(const uchar4*)(M2u8 + wc * 256 + mt * 32 + s * 16 + q * 4);
            acc[mt][s][0] = mv.x ? acc[mt][s][0] : NEGC;
            acc[mt][s][1] = mv.y ? acc[mt][s][1] : NEGC;
            acc[mt][s][2] = mv.z ? acc[mt][s][2] : NEGC;
            acc[mt][s][3] = mv.w ? acc[mt][s][3] : NEGC;
        }
    float rmax = NEGC;
#pragma unroll
    for (int mt = 0; mt < 8; ++mt)
#pragma unroll
        for (int s = 0; s < 2; ++s)
#pragma unroll
            for (int r = 0; r < 4; ++r) rmax = fmaxf(rmax, acc[mt][s][r]);
    rmax = fmaxf(rmax, __shfl_xor(rmax, 16));
    rmax = fmaxf(rmax, __shfl_xor(rmax, 32));
    if (q == 0) REDm[wc * 32 + wr * 16 + fr] = rmax;
    __syncthreads();
    const float RM = fmaxf(REDm[wr * 16 + fr], REDm[32 + wr * 16 + fr]);
    if (t < 32) {  // a1 logits
        float v = fmaxf(REDm[t], REDm[32 + t]);
        float m1v = (float)m1[b * 2048 + n0 + t];
        a1log[b * 2048 + n0 + t] = v + (1.0f - m1v) * NEGC;
    }
    float rs = 0.f;
#pragma unroll
    for (int mt = 0; mt < 8; ++mt)
#pragma unroll
        for (int s = 0; s < 2; ++s)
#pragma unroll
            for (int r = 0; r < 4; ++r) {
                float e = __expf(acc[mt][s][r] - RM);
                acc[mt][s][r] = e;
                rs += e;
            }
    rs += __shfl_xor(rs, 16);
    rs += __shfl_xor(rs, 32);
    if (q == 0) REDs[wc * 32 + wr * 16 + fr] = rs;
    __syncthreads();
    const float rinv = 1.0f / (REDs[wr * 16 + fr] + REDs[32 + wr * 16 + fr]);

    // issue VT(0), VT(1): fly under normalize + pb-build below
    stageT(0, 0);
    stageT(1, 1);

    // normalize in place (a2 values, stored at the very end from regs)
#pragma unroll
    for (int mt = 0; mt < 8; ++mt)
#pragma unroll
        for (int s = 0; s < 2; ++s)
#pragma unroll
            for (int r = 0; r < 4; ++r) acc[mt][s][r] *= rinv;

    // ---- build PV B-fragments from registers (no LDS): pb[ks2] = P[n=wr*16+fr][m-local ks2*32+q*8+j]
    bf16x8 pb[8];
#pragma unroll
    for (int ks2 = 0; ks2 < 8; ++ks2) {
        unsigned short pk[8];
#pragma unroll
        for (int j = 0; j < 8; ++j) {
            int qs = (((q & 1) << 3) + j) >> 2;        // src q-group
            int src = (qs << 4) + fr;
            float y0 = __shfl(acc[ks2][0][j & 3], src);
            float y1 = __shfl(acc[ks2][1][j & 3], src);
            pk[j] = f2bf((q >> 1) ? y1 : y0);
        }
        pb[ks2] = *(bf16x8*)pk;
    }

    // ---- phase C: out0^T partials = V^T . P^T over own m-half; counted-vmcnt dbuf ----
    f32x4 oacc[8];
#pragma unroll
    for (int dt = 0; dt < 8; ++dt) oacc[dt] = (f32x4){0.f, 0.f, 0.f, 0.f};

#pragma unroll
    for (int dt = 0; dt < 8; ++dt) {
        if (dt == 7) { VMCNT(0); } else { VMCNT(4); }
        SBARM;
        {
            const char* Tb = smem + (dt & 1) * 16384;
            const int sw = (fr & 7) << 4;
            f32x4 o = oacc[dt];
#pragma unroll
            for (int ks2 = 0; ks2 < 8; ++ks2) {
                int aoff = (fr * 1024 + wc * 512 + ks2 * 64 + q * 16) ^ sw;
                bf16x8 av = *(const bf16x8*)(Tb + aoff);
                o = __builtin_amdgcn_mfma_f32_16x16x32_bf16(av, pb[ks2], o, 0, 0, 0);
            }
            oacc[dt] = o;
        }
        LGKMCNT0;
        SBARM;
        if (dt < 6) stageT(dt & 1, dt + 2);
    }

    // ---- cross-wc partial reduce + stores ----
    // oacc[dt] lane (q,fr): out0^T[d = dt*16+q*4+r][n = wr*16+fr], summed over wc's m-half.
    float* Pex = (float*)smem;   // [2 wr][16 n][132]
    const size_t orow = (size_t)(b * 2048 + n0 + wr * 16 + fr);
    if (wc == 1) {
#pragma unroll
        for (int dt = 0; dt < 8; ++dt)
            *(f32x4*)(Pex + wr * 2112 + fr * 132 + dt * 16 + q * 4) = oacc[dt];
    } else {
        // a2 stores for wc=0 half (float4: r-contiguous m)
#pragma unroll
        for (int mt = 0; mt < 8; ++mt)
#pragma unroll
            for (int s = 0; s < 2; ++s)
                *(f32x4*)(a2out + orow * 512 + mt * 32 + s * 16 + q * 4) = acc[mt][s];
    }
    __syncthreads();
    if (wc == 0) {
#pragma unroll
        for (int dt = 0; dt < 8; ++dt) {
            f32x4 p = *(const f32x4*)(Pex + wr * 2112 + fr * 132 + dt * 16 + q * 4);
            f32x4 o = oacc[dt];
            o[0] += p[0]; o[1] += p[1]; o[2] += p[2]; o[3] += p[3];
            *(f32x4*)(out0 + orow * 128 + dt * 16 + q * 4) = o;
        }
    } else {
        // a2 stores for wc=1 half
#pragma unroll
        for (int mt = 0; mt < 8; ++mt)
#pragma unroll
            for (int s = 0; s < 2; ++s)
                *(f32x4*)(a2out + orow * 512 + 256 + mt * 32 + s * 16 + q * 4) = acc[mt][s];
    }
}

// ---- a1 softmax over n (also zero-inits out2 for k_gemv's atomics) ----
__global__ __launch_bounds__(256) void k_a1(float* __restrict__ a1slot,
                                            float* __restrict__ out2) {
    __shared__ float wred[4];
    const int b = blockIdx.x, t = threadIdx.x, lane = t & 63, w = t >> 6;

    if (t < 128) out2[b * 128 + t] = 0.f;

    const float4* Lp = (const float4*)(a1slot + (size_t)b * 2048);
    float4 La = Lp[t * 2], Lb = Lp[t * 2 + 1];
    float l[8] = {La.x, La.y, La.z, La.w, Lb.x, Lb.y, Lb.z, Lb.w};

    float lmax = l[0];
#pragma unroll
    for (int j = 1; j < 8; ++j) lmax = fmaxf(lmax, l[j]);
#pragma unroll
    for (int off = 1; off < 64; off <<= 1) lmax = fmaxf(lmax, __shfl_xor(lmax, off));
    if (lane == 0) wred[w] = lmax;
    __syncthreads();
    float bmax = fmaxf(fmaxf(wred[0], wred[1]), fmaxf(wred[2], wred[3]));

    float e[8]; float s = 0.f;
#pragma unroll
    for (int j = 0; j < 8; ++j) { e[j] = __expf(l[j] - bmax); s += e[j]; }
#pragma unroll
    for (int off = 1; off < 64; off <<= 1) s += __shfl_xor(s, off);
    __syncthreads();
    if (lane == 0) wred[w] = s;
    __syncthreads();
    float inv = 1.0f / (wred[0] + wred[1] + wred[2] + wred[3]);

    float4 o1{e[0] * inv, e[1] * inv, e[2] * inv, e[3] * inv};
    float4 o2v{e[4] * inv, e[5] * inv, e[6] * inv, e[7] * inv};
    ((float4*)(a1slot + (size_t)b * 2048))[t * 2] = o1;
    ((float4*)(a1slot + (size_t)b * 2048))[t * 2 + 1] = o2v;
}

// ---- GEMV: out2 += a1 . seq1 over 256-row chunks (atomic accumulate) ----
__global__ __launch_bounds__(256) void k_gemv(const float* __restrict__ seq1,
                                              const float* __restrict__ a1,
                                              float* __restrict__ out2) {
    __shared__ float a1b[256];
    __shared__ float4 red[8][32];
    const int bid = blockIdx.x, b = bid >> 3, ch = bid & 7, t = threadIdx.x;
    const int n0 = ch * 256;
    if (t < 64) ((float4*)a1b)[t] = ((const float4*)(a1 + (size_t)b * 2048 + n0))[t];
    __syncthreads();
    const int d4 = t & 31, sl = t >> 5;
    float4 acc{0.f, 0.f, 0.f, 0.f};
    const float4* s1 = (const float4*)(seq1 + (size_t)(b * 2048 + n0 + sl * 32) * 128);
#pragma unroll 8
    for (int j = 0; j < 32; ++j) {
        float wv = a1b[sl * 32 + j];
        float4 v = s1[j * 32 + d4];
        acc.x += wv * v.x; acc.y += wv * v.y; acc.z += wv * v.z; acc.w += wv * v.w;
    }
    red[sl][d4] = acc;
    __syncthreads();
    if (t < 32) {
        float4 s0 = red[0][t];
#pragma unroll
        for (int c = 1; c < 8; ++c) {
            float4 v = red[c][t];
            s0.x += v.x; s0.y += v.y; s0.z += v.z; s0.w += v.w;
        }
        float* dst = out2 + b * 128 + t * 4;
        atomicAdd(dst + 0, s0.x);
        atomicAdd(dst + 1, s0.y);
        atomicAdd(dst + 2, s0.z);
        atomicAdd(dst + 3, s0.w);
    }
}

extern "C" void kernel_launch(void* const* d_in, const int* in_sizes, int n_in,
                              void* d_out, int out_size, void* d_ws, size_t ws_size,
                              hipStream_t stream) {
    const float* seq1 = (const float*)d_in[0];
    const float* seq2 = (const float*)d_in[1];
    const int*   m1   = (const int*)d_in[2];
    const int*   m2   = (const int*)d_in[3];
    (void)d_ws; (void)ws_size; (void)n_in; (void)in_sizes;

    float* out  = (float*)d_out;
    float* out0 = out;                 // [32,2048,128]
    float* a2o  = out + 8388608;       // [32,2048,512]
    float* o2   = out + 41943040;      // [32,128]
    float* a1o  = out + 41947136;      // [32,2048] (logits then final a1)

    k_prep<<<dim3(512), dim3(256), 0, stream>>>(seq2);
    bidir_main<<<dim3(2048), dim3(256), 0, stream>>>(seq1, m1, m2, out0, a2o, a1o);
    k_a1<<<dim3(32), dim3(256), 0, stream>>>(a1o, o2);
    k_gemv<<<dim3(256), dim3(256), 0, stream>>>(seq1, a1o, o2);
}